// Round 8
// baseline (111.164 us; speedup 1.0000x reference)
//
#include <hip/hip_runtime.h>

#define NB 8
#define LEN 256
#define DIM 768
#define NC 3976
#define NCAND (NB * NC)  // 31808
// output layout (floats): fofe_codes [8][3976][5][768] = 122142720,
// cands_pos [8][3976][2] = 63616, padded [8][3976] = 31808
#define OFF_POS 122142720
#define OFF_PAD (122142720 + 63616)
#define NBLK 2048

constexpr float ALPHA_F = 0.9f;
constexpr float A32 = 0.03433683820292512f;  // 0.9^32

typedef float f4 __attribute__((ext_vector_type(4)));

__device__ __constant__ float APOW[17] = {
    1.f, 0.9f, 0.81f, 0.729f, 0.6561f, 0.59049f, 0.531441f, 0.4782969f,
    0.43046721f, 0.387420489f, 0.3486784401f, 0.31381059609f, 0.282429536481f,
    0.2541865828329f, 0.22876792454961f, 0.205891132094649f, 0.1853020188851841f};

// Prefix/suffix geometric scan: P[l] = x[l] + a*P[l-1], S[l] = x[l] + a*S[l+1].
// block = 256 threads: 32 d-lanes x 8 l-chunks (32 elems each).
// grid = (DIM/32 = 24, NB, 2 directions)
__global__ __launch_bounds__(256) void scan_kernel(const float* __restrict__ x,
                                                   float* __restrict__ P,
                                                   float* __restrict__ S) {
    const int dl = threadIdx.x & 31;
    const int chunk = threadIdx.x >> 5;
    const int d = blockIdx.x * 32 + dl;
    const int b = blockIdx.y;
    const int dir = blockIdx.z;
    const float* __restrict__ xb = x + (size_t)b * LEN * DIM;
    float* __restrict__ ob = (dir ? S : P) + (size_t)b * LEN * DIM;

    float vals[32];
    float acc = 0.f;
#pragma unroll
    for (int t = 0; t < 32; ++t) {
        const int lm = chunk * 32 + t;
        const int l = dir ? (LEN - 1 - lm) : lm;
        acc = fmaf(ALPHA_F, acc, xb[l * DIM + d]);
        vals[t] = acc;
    }

    __shared__ float ends[8][32];
    ends[chunk][dl] = acc;
    __syncthreads();

    // carry into this chunk: C_k = end[k-1] + a^32 * C_{k-1}
    float carry = 0.f;
    for (int k = 0; k < chunk; ++k)
        carry = fmaf(A32, carry, ends[k][dl]);

    float w = ALPHA_F;
#pragma unroll
    for (int t = 0; t < 32; ++t) {
        const int lm = chunk * 32 + t;
        const int l = dir ? (LEN - 1 - lm) : lm;
        ob[l * DIM + d] = fmaf(w, carry, vals[t]);
        w *= ALPHA_F;
    }
}

// Candidate-granular grid-stride sweep: at step q all NBLK blocks process
// candidates q*NBLK..q*NBLK+NBLK-1 — each block does 4 L2 reads (pm1,pe,si,se1)
// then writes 15 KB contiguous (5 rows); the grid writes a contiguous ~31 MB
// window advancing linearly through the 489 MB output. 1-deep software
// pipeline: next candidate's loads issue before current candidate's stores.
__global__ __launch_bounds__(192) void cand_kernel(const float* __restrict__ P,
                                                   const float* __restrict__ S,
                                                   const int* __restrict__ mask,
                                                   float* __restrict__ out) {
    const int t = threadIdx.x;
    const f4* __restrict__ P4 = (const f4*)P;
    const f4* __restrict__ S4 = (const f4*)S;
    f4* __restrict__ out4 = (f4*)out;

    // decode + load helper (all block-uniform control)
#define DECODE_LOAD(BC, PM1, PE, SI, SE1, SS)                               \
    {                                                                       \
        const int b_ = (BC) / NC;                                           \
        const int c_ = (BC) - b_ * NC;                                      \
        int i_, s_;                                                         \
        if (c_ < 3856) {                                                    \
            i_ = c_ >> 4;                                                   \
            s_ = c_ & 15;                                                   \
        } else {                                                            \
            const int r_ = c_ - 3856;                                       \
            int u_ = 0, off_ = 0;                                           \
            while (off_ + (15 - u_) <= r_) { off_ += 15 - u_; ++u_; }       \
            i_ = 241 + u_;                                                  \
            s_ = r_ - off_;                                                 \
        }                                                                   \
        const int e_ = i_ + s_;                                             \
        const int base_ = b_ * LEN;                                         \
        PM1 = (i_ > 0) ? P4[(size_t)(base_ + i_ - 1) * 192 + t] : (f4)0.f;  \
        PE = P4[(size_t)(base_ + e_) * 192 + t];                            \
        SI = S4[(size_t)(base_ + i_) * 192 + t];                            \
        SE1 = (e_ < LEN - 1) ? S4[(size_t)(base_ + e_ + 1) * 192 + t] : (f4)0.f; \
        SS = s_;                                                            \
    }

    int bc = blockIdx.x;
    f4 cpm1, cpe, csi, cse1;
    int cs;
    DECODE_LOAD(bc, cpm1, cpe, csi, cse1, cs);

    for (;;) {
        const int bn = bc + NBLK;
        const bool hn = bn < NCAND;
        f4 npm1, npe, nsi, nse1;
        int ns;
        if (hn) DECODE_LOAD(bn, npm1, npe, nsi, nse1, ns);  // read-ahead

        const f4 cand = cpe - APOW[cs + 1] * cpm1;
        f4* o = out4 + (size_t)bc * 960 + t;
        o[0 * 192] = cpm1;  // [left_excl, left_incl, cand, right_incl, right_excl]
        o[1 * 192] = cpe;
        o[2 * 192] = cand;
        o[3 * 192] = csi;
        o[4 * 192] = cse1;

        if (!hn) break;
        cpm1 = npm1; cpe = npe; csi = nsi; cse1 = nse1; cs = ns;
        bc = bn;
    }

    // tail: cands_pos + padded_cands, one (b, start i) per block
    {
        const int r2 = blockIdx.x;
        const int b = r2 >> 8;
        const int i = r2 & 255;
        int n, c0;
        if (i <= 240) {
            n = 16;
            c0 = i * 16;
        } else {
            const int r = LEN - i;  // 15..1
            n = r;
            c0 = 3856 + 120 - r * (r + 1) / 2;
        }
        if (t < 64) {  // wave 0 only
            const int m = (t < n) ? mask[b * LEN + i + t] : 0;
            const unsigned long long ball = __ballot(m != 0);
            if (t < n) {
                const size_t c = (size_t)(b * NC + c0 + t);
                out[OFF_POS + c * 2] = (float)i;
                out[OFF_POS + c * 2 + 1] = (float)(i + t);
                // window [i, i+t]: any mask bit among ballot bits 0..t
                out[OFF_PAD + c] = (ball & ((2ull << t) - 1)) ? 1.f : 0.f;
            }
        }
    }
#undef DECODE_LOAD
}

extern "C" void kernel_launch(void* const* d_in, const int* in_sizes, int n_in,
                              void* d_out, int out_size, void* d_ws, size_t ws_size,
                              hipStream_t stream) {
    const float* x = (const float*)d_in[0];
    const int* mask = (const int*)d_in[1];
    float* out = (float*)d_out;
    float* P = (float*)d_ws;                  // [8][256][768] fp32
    float* S = P + (size_t)NB * LEN * DIM;    // [8][256][768] fp32  (12.6 MB total)

    scan_kernel<<<dim3(DIM / 32, NB, 2), 256, 0, stream>>>(x, P, S);
    cand_kernel<<<NBLK, 192, 0, stream>>>(P, S, mask, out);
}

// Round 9
// 104.531 us; speedup vs baseline: 1.0635x; 1.0635x over previous
//
#include <hip/hip_runtime.h>

#define NB 8
#define LEN 256
#define DIM 768
#define NC 3976
// output layout (floats): fofe_codes [8][3976][5][768] = 122142720,
// cands_pos [8][3976][2] = 63616, padded [8][3976] = 31808
#define OFF_POS 122142720
#define OFF_PAD (122142720 + 63616)
#define NROWS (NB * NC * 5)        // 159040 fofe rows of 768 floats
#define NVROWS (NROWS + NB * LEN)  // + 2048 virtual rows for pos/pad
#define NBLK 2048

constexpr float ALPHA_F = 0.9f;
constexpr float A32 = 0.03433683820292512f;  // 0.9^32

typedef float f4 __attribute__((ext_vector_type(4)));
typedef float f2 __attribute__((ext_vector_type(2)));
typedef unsigned int u32;
typedef u32 u2 __attribute__((ext_vector_type(2)));

__device__ __constant__ float APOW[17] = {
    1.f, 0.9f, 0.81f, 0.729f, 0.6561f, 0.59049f, 0.531441f, 0.4782969f,
    0.43046721f, 0.387420489f, 0.3486784401f, 0.31381059609f, 0.282429536481f,
    0.2541865828329f, 0.22876792454961f, 0.205891132094649f, 0.1853020188851841f};

__device__ inline u32 pack_bf16x2(float a, float b) {  // RNE
    u32 ua = __float_as_uint(a), ub = __float_as_uint(b);
    ua = (ua + 0x7fffu + ((ua >> 16) & 1u)) >> 16;
    ub = (ub + 0x7fffu + ((ub >> 16) & 1u)) >> 16;
    return ua | (ub << 16);
}

// Prefix/suffix geometric scan with bf16 output (halves P/S traffic).
// block = 256 threads: 32 dpair-lanes (2 consecutive d each) x 8 l-chunks.
// grid = (DIM/64 = 12, NB, 2 directions)
__global__ __launch_bounds__(256) void scan_kernel(const float* __restrict__ x,
                                                   unsigned short* __restrict__ P,
                                                   unsigned short* __restrict__ S) {
    const int dl = threadIdx.x & 31;
    const int chunk = threadIdx.x >> 5;
    const int dp = blockIdx.x * 32 + dl;  // float2 index within row (DIM/2=384)
    const int b = blockIdx.y;
    const int dir = blockIdx.z;
    const f2* __restrict__ xb = (const f2*)(x + (size_t)b * LEN * DIM);
    u32* __restrict__ ob = (u32*)((dir ? S : P) + (size_t)b * LEN * DIM);

    f2 vals[32];
    f2 acc = (f2)0.f;
#pragma unroll
    for (int t = 0; t < 32; ++t) {
        const int lm = chunk * 32 + t;
        const int l = dir ? (LEN - 1 - lm) : lm;
        acc = acc * ALPHA_F + xb[l * 384 + dp];
        vals[t] = acc;
    }

    __shared__ f2 ends[8][32];
    ends[chunk][dl] = acc;
    __syncthreads();

    // carry into this chunk: C_k = end[k-1] + a^32 * C_{k-1}
    f2 carry = (f2)0.f;
    for (int k = 0; k < chunk; ++k)
        carry = carry * A32 + ends[k][dl];

    float w = ALPHA_F;
#pragma unroll
    for (int t = 0; t < 32; ++t) {
        const int lm = chunk * 32 + t;
        const int l = dir ? (LEN - 1 - lm) : lm;
        const f2 v = vals[t] + carry * w;
        ob[l * 384 + dp] = pack_bf16x2(v.x, v.y);
        w *= ALPHA_F;
    }
}

// bf16 row fragment -> f4 (lane t covers elements 4t..4t+3 of a 768-elem row)
__device__ inline f4 ld_row(const unsigned short* __restrict__ row, int t) {
    const u2 p = *(const u2*)(row + t * 4);
    f4 v;
    v.x = __uint_as_float(p.x << 16);
    v.y = __uint_as_float(p.x & 0xffff0000u);
    v.z = __uint_as_float(p.y << 16);
    v.w = __uint_as_float(p.y & 0xffff0000u);
    return v;
}

// Grid-stride ROW SWEEP (R7 structure, bf16 P/S reads): at step q all NBLK
// blocks write rows q*NBLK.. — a contiguous ~6 MB window advancing linearly
// through the 489 MB output. One 3072 B row per block per step.
__global__ __launch_bounds__(192) void row_kernel(const unsigned short* __restrict__ P,
                                                  const unsigned short* __restrict__ S,
                                                  const int* __restrict__ mask,
                                                  float* __restrict__ out) {
    const int t = threadIdx.x;
    f4* __restrict__ out4 = (f4*)out;

    for (int row = blockIdx.x; row < NVROWS; row += NBLK) {
        if (row < NROWS) {
            const int bc = row / 5;
            const int which = row - bc * 5;
            const int b = bc / NC;
            const int c = bc - b * NC;
            // decode candidate c -> (start i, span s)
            int i, s;
            if (c < 3856) {
                i = c >> 4;
                s = c & 15;
            } else {
                const int r = c - 3856;
                int u = 0, off = 0;
                while (off + (15 - u) <= r) { off += 15 - u; ++u; }
                i = 241 + u;
                s = r - off;
            }
            const int e = i + s;
            const size_t base = (size_t)(b * LEN);
            f4 v;
            if (which == 0) {  // left excl: P[i-1]
                v = (i > 0) ? ld_row(P + (base + i - 1) * DIM, t) : (f4)0.f;
            } else if (which == 1) {  // left incl: P[e]
                v = ld_row(P + (base + e) * DIM, t);
            } else if (which == 2) {  // cand: P[e] - a^(s+1)*P[i-1]
                v = ld_row(P + (base + e) * DIM, t);
                if (i > 0) v = v - APOW[s + 1] * ld_row(P + (base + i - 1) * DIM, t);
            } else if (which == 3) {  // right incl: S[i]
                v = ld_row(S + (base + i) * DIM, t);
            } else {  // right excl: S[e+1]
                v = (e < LEN - 1) ? ld_row(S + (base + e + 1) * DIM, t) : (f4)0.f;
            }
            out4[(size_t)row * 192 + t] = v;
        } else {
            // virtual rows: cands_pos + padded_cands for one (b, start i)
            const int r2 = row - NROWS;
            const int b = r2 >> 8;
            const int i = r2 & 255;
            int n, c0;
            if (i <= 240) {
                n = 16;
                c0 = i * 16;
            } else {
                const int r = LEN - i;  // 15..1
                n = r;
                c0 = 3856 + 120 - r * (r + 1) / 2;
            }
            if (t < 64) {  // wave 0 only
                const int m = (t < n) ? mask[b * LEN + i + t] : 0;
                const unsigned long long ball = __ballot(m != 0);
                if (t < n) {
                    const size_t c = (size_t)(b * NC + c0 + t);
                    out[OFF_POS + c * 2] = (float)i;
                    out[OFF_POS + c * 2 + 1] = (float)(i + t);
                    // window [i, i+t]: any mask bit among ballot bits 0..t
                    out[OFF_PAD + c] = (ball & ((2ull << t) - 1)) ? 1.f : 0.f;
                }
            }
        }
    }
}

extern "C" void kernel_launch(void* const* d_in, const int* in_sizes, int n_in,
                              void* d_out, int out_size, void* d_ws, size_t ws_size,
                              hipStream_t stream) {
    const float* x = (const float*)d_in[0];
    const int* mask = (const int*)d_in[1];
    float* out = (float*)d_out;
    unsigned short* P = (unsigned short*)d_ws;       // [8][256][768] bf16
    unsigned short* S = P + (size_t)NB * LEN * DIM;  // [8][256][768] bf16 (6.3 MB total)

    scan_kernel<<<dim3(DIM / 64, NB, 2), 256, 0, stream>>>(x, P, S);
    row_kernel<<<NBLK, 192, 0, stream>>>(P, S, mask, out);
}

// Round 10
// 102.649 us; speedup vs baseline: 1.0830x; 1.0183x over previous
//
#include <hip/hip_runtime.h>

#define NB 8
#define LEN 256
#define DIM 768
#define NC 3976
// output layout (floats): fofe_codes [8][3976][5][768] = 122142720,
// cands_pos [8][3976][2] = 63616, padded [8][3976] = 31808
#define OFF_POS 122142720
#define OFF_PAD (122142720 + 63616)
#define BROWS (NC * 5)  // 19880 fofe rows per batch
#define NBLK 2048

constexpr float ALPHA_F = 0.9f;
constexpr float A32 = 0.03433683820292512f;  // 0.9^32

typedef float f4 __attribute__((ext_vector_type(4)));

__device__ __constant__ float APOW[17] = {
    1.f, 0.9f, 0.81f, 0.729f, 0.6561f, 0.59049f, 0.531441f, 0.4782969f,
    0.43046721f, 0.387420489f, 0.3486784401f, 0.31381059609f, 0.282429536481f,
    0.2541865828329f, 0.22876792454961f, 0.205891132094649f, 0.1853020188851841f};

// Prefix/suffix geometric scan: P[l] = x[l] + a*P[l-1], S[l] = x[l] + a*S[l+1].
// 1D grid of 384 blocks, decoded so batch = id%8 -> batch b's P/S is PRODUCED
// on XCD b (round-robin dispatch) and stays resident in that XCD's L2 for the
// row kernel (same pinning) to consume without an HBM round-trip.
__global__ __launch_bounds__(256) void scan_kernel(const float* __restrict__ x,
                                                   float* __restrict__ P,
                                                   float* __restrict__ S) {
    const int lid = blockIdx.x;
    const int b = lid & 7;
    const int sub = lid >> 3;      // 0..47
    const int dir = sub & 1;
    const int dchunk = sub >> 1;   // 0..23
    const int dl = threadIdx.x & 31;
    const int chunk = threadIdx.x >> 5;
    const int d = dchunk * 32 + dl;
    const float* __restrict__ xb = x + (size_t)b * LEN * DIM;
    float* __restrict__ ob = (dir ? S : P) + (size_t)b * LEN * DIM;

    float vals[32];
    float acc = 0.f;
#pragma unroll
    for (int t = 0; t < 32; ++t) {
        const int lm = chunk * 32 + t;
        const int l = dir ? (LEN - 1 - lm) : lm;
        acc = fmaf(ALPHA_F, acc, xb[l * DIM + d]);
        vals[t] = acc;
    }

    __shared__ float ends[8][32];
    ends[chunk][dl] = acc;
    __syncthreads();

    // carry into this chunk: C_k = end[k-1] + a^32 * C_{k-1}
    float carry = 0.f;
    for (int k = 0; k < chunk; ++k)
        carry = fmaf(A32, carry, ends[k][dl]);

    float w = ALPHA_F;
#pragma unroll
    for (int t = 0; t < 32; ++t) {
        const int lm = chunk * 32 + t;
        const int l = dir ? (LEN - 1 - lm) : lm;
        ob[l * DIM + d] = fmaf(w, carry, vals[t]);
        w *= ALPHA_F;
    }
}

// XCD-pinned grid-stride ROW SWEEP: b = blockIdx.x & 7 (round-robin XCD), so
// each XCD reads ONLY its batch's 3.1 MB P/S slice (fits 4 MiB L2) instead of
// all 8 XCDs refetching every batch (~100 MB duplicated HBM fetch in R7).
// 256 blocks per batch sweep its contiguous 61 MB output region in row order:
// contiguous 768 KB window per batch per step, advancing linearly.
__global__ __launch_bounds__(192) void row_kernel(const float* __restrict__ P,
                                                  const float* __restrict__ S,
                                                  const int* __restrict__ mask,
                                                  float* __restrict__ out) {
    const int t = threadIdx.x;
    const int b = blockIdx.x & 7;
    const int k2 = blockIdx.x >> 3;  // 0..255 within batch
    const f4* __restrict__ P4 = (const f4*)(P + (size_t)b * LEN * DIM);
    const f4* __restrict__ S4 = (const f4*)(S + (size_t)b * LEN * DIM);
    f4* __restrict__ out4 = (f4*)out + (size_t)b * BROWS * 192;

    for (int r = k2; r < BROWS + LEN; r += 256) {
        if (r < BROWS) {
            const int c = r / 5;
            const int which = r - c * 5;
            // decode candidate c -> (start i, span s)
            int i, s;
            if (c < 3856) {
                i = c >> 4;
                s = c & 15;
            } else {
                const int rr = c - 3856;
                int u = 0, off = 0;
                while (off + (15 - u) <= rr) { off += 15 - u; ++u; }
                i = 241 + u;
                s = rr - off;
            }
            const int e = i + s;
            f4 v;
            if (which == 0) {  // left excl: P[i-1]
                v = (i > 0) ? P4[(size_t)(i - 1) * 192 + t] : (f4)0.f;
            } else if (which == 1) {  // left incl: P[e]
                v = P4[(size_t)e * 192 + t];
            } else if (which == 2) {  // cand: P[e] - a^(s+1)*P[i-1]
                v = P4[(size_t)e * 192 + t];
                if (i > 0) v = v - APOW[s + 1] * P4[(size_t)(i - 1) * 192 + t];
            } else if (which == 3) {  // right incl: S[i]
                v = S4[(size_t)i * 192 + t];
            } else {  // right excl: S[e+1]
                v = (e < LEN - 1) ? S4[(size_t)(e + 1) * 192 + t] : (f4)0.f;
            }
            out4[(size_t)r * 192 + t] = v;
        } else {
            // one virtual row per block: cands_pos + padded_cands for (b, i)
            const int i = r - BROWS;
            int n, c0;
            if (i <= 240) {
                n = 16;
                c0 = i * 16;
            } else {
                const int rr = LEN - i;  // 15..1
                n = rr;
                c0 = 3856 + 120 - rr * (rr + 1) / 2;
            }
            if (t < 64) {  // wave 0 only
                const int m = (t < n) ? mask[b * LEN + i + t] : 0;
                const unsigned long long ball = __ballot(m != 0);
                if (t < n) {
                    const size_t c = (size_t)(b * NC + c0 + t);
                    out[OFF_POS + c * 2] = (float)i;
                    out[OFF_POS + c * 2 + 1] = (float)(i + t);
                    // window [i, i+t]: any mask bit among ballot bits 0..t
                    out[OFF_PAD + c] = (ball & ((2ull << t) - 1)) ? 1.f : 0.f;
                }
            }
        }
    }
}

extern "C" void kernel_launch(void* const* d_in, const int* in_sizes, int n_in,
                              void* d_out, int out_size, void* d_ws, size_t ws_size,
                              hipStream_t stream) {
    const float* x = (const float*)d_in[0];
    const int* mask = (const int*)d_in[1];
    float* out = (float*)d_out;
    float* P = (float*)d_ws;                  // [8][256][768] fp32
    float* S = P + (size_t)NB * LEN * DIM;    // [8][256][768] fp32  (12.6 MB total)

    scan_kernel<<<384, 256, 0, stream>>>(x, P, S);
    row_kernel<<<NBLK, 192, 0, stream>>>(P, S, mask, out);
}